// Round 16
// baseline (980.540 us; speedup 1.0000x reference)
//
#include <hip/hip_runtime.h>
#include <hip/hip_bf16.h>

constexpr int cB = 32, cN = 64, cL = 64, cT = 10, cD = 256, cH = 512, cH3 = 1536;
constexpr int cBN = cB * cN;   // 2048
constexpr int cNP1 = cN + 1;   // 65: hidden tape, slot 0 = h0, slot n+1 = hs[:,n,:]

typedef __bf16 bf16x8 __attribute__((ext_vector_type(8)));
typedef float f32x4 __attribute__((ext_vector_type(4)));

__device__ __forceinline__ ushort f2bf(float f) {
  __hip_bfloat16 h = __float2bfloat16(f);
  return *reinterpret_cast<ushort*>(&h);
}
__device__ __forceinline__ float bf2f(ushort u) {
  return __uint_as_float(((unsigned)u) << 16);
}

// ---------------- x[bn][d] = sum_l emb[sents[bn][l]][d] ----------------
__global__ void k_embed_x(const int* __restrict__ sents, const float* __restrict__ emb,
                          float* __restrict__ x) {
  __shared__ int idx[cL];
  int bn = blockIdx.x, t = threadIdx.x;
  if (t < cL) idx[t] = sents[bn * cL + t];
  __syncthreads();
  float acc = 0.f;
#pragma unroll 8
  for (int l = 0; l < cL; ++l) acc += emb[(long)idx[l] * cD + t];
  x[bn * cD + t] = acc;
}

// ---------------- tsum[b][d] = sum_t emb[titles[b][0][t]][d] ----------------
__global__ void k_title(const int* __restrict__ titles, const float* __restrict__ emb,
                        float* __restrict__ tsum) {
  __shared__ int idx[cT];
  int b = blockIdx.x, t = threadIdx.x;
  if (t < cT) idx[t] = titles[b * cN * cT + t];
  __syncthreads();
  float acc = 0.f;
#pragma unroll
  for (int i = 0; i < cT; ++i) acc += emb[(long)idx[i] * cD + t];
  tsum[b * cD + t] = acc;
}

// ---------------- h0 = tsum @ Wt + bt -> hse slot 0 ----------------
__global__ void k_h0(const float* __restrict__ tsum, const float* __restrict__ Wt,
                     const float* __restrict__ bt, float* __restrict__ hse) {
  int i = blockIdx.x * blockDim.x + threadIdx.x;  // B*H
  int b = i >> 9, hh = i & (cH - 1);
  const float* ts = tsum + b * cD;
  float acc = bt[hh];
  for (int k = 0; k < cD; ++k) acc += ts[k] * Wt[(long)k * cH + hh];
  hse[(long)b * cNP1 * cH + hh] = acc;
}

// ---------------- GI = X @ W_ih + b_ih ----------------
// grid (3 cg, 512 rowg); block 128; C=4 cols/thread, M=4 rows/block
__global__ void __launch_bounds__(128, 3) k_gi(
    const float* __restrict__ x, const float* __restrict__ W_ih,
    const float* __restrict__ b_ih, float* __restrict__ gi) {
  __shared__ float4 s4[4 * 64];                    // 4 rows x 256 k (4 KB)
  int cg = blockIdx.x;
  int row0 = blockIdx.y * 4;
  int t = threadIdx.x;
  const float4* x4 = (const float4*)(x + (long)row0 * cD);
  for (int i = t; i < 4 * 64; i += 128) s4[i] = x4[i];  // rows contiguous
  __syncthreads();
  int col0 = cg * 512 + t * 4;
  float4 acc[4];
#pragma unroll
  for (int m = 0; m < 4; ++m) acc[m] = make_float4(0.f, 0.f, 0.f, 0.f);
#pragma unroll 8
  for (int k4 = 0; k4 < 64; ++k4) {
    const float* wrow = W_ih + (long)(k4 * 4) * cH3 + col0;
    float4 w0 = *(const float4*)(wrow);
    float4 w1 = *(const float4*)(wrow + cH3);
    float4 w2 = *(const float4*)(wrow + 2 * cH3);
    float4 w3 = *(const float4*)(wrow + 3 * cH3);
#pragma unroll
    for (int m = 0; m < 4; ++m) {
      float4 a = s4[m * 64 + k4];
      acc[m].x += a.x * w0.x + a.y * w1.x + a.z * w2.x + a.w * w3.x;
      acc[m].y += a.x * w0.y + a.y * w1.y + a.z * w2.y + a.w * w3.y;
      acc[m].z += a.x * w0.z + a.y * w1.z + a.z * w2.z + a.w * w3.z;
      acc[m].w += a.x * w0.w + a.y * w1.w + a.z * w2.w + a.w * w3.w;
    }
  }
  float4 bb = *(const float4*)(b_ih + col0);
#pragma unroll
  for (int m = 0; m < 4; ++m)
    *(float4*)(gi + (long)(row0 + m) * cH3 + col0) =
        make_float4(acc[m].x + bb.x, acc[m].y + bb.y, acc[m].z + bb.z, acc[m].w + bb.w);
}

// ---------------- W_hh -> transposed split-bf16: Whi/Wlo[col][k] ----------------
// grid (24 colg, 8 kg); block 256; LDS-tiled transpose
__global__ void k_whhsplit(const float* __restrict__ W, ushort* __restrict__ whi,
                           ushort* __restrict__ wlo) {
  __shared__ float tile[64][65];
  int col0 = blockIdx.x * 64, k0 = blockIdx.y * 64;
  int t = threadIdx.x;
  for (int i = t; i < 4096; i += 256) {
    int kr = i >> 6, cc = i & 63;
    tile[kr][cc] = W[(long)(k0 + kr) * cH3 + col0 + cc];
  }
  __syncthreads();
  for (int i = t; i < 4096; i += 256) {
    int cc = i >> 6, kr = i & 63;
    float w = tile[kr][cc];
    ushort hi = f2bf(w);
    ushort lo = f2bf(w - bf2f(hi));
    whi[(long)(col0 + cc) * cH + k0 + kr] = hi;
    wlo[(long)(col0 + cc) * cH + k0 + kr] = lo;
  }
}

// ---------------- h0 -> split-bf16 parity-0 buffers ----------------
__global__ void k_hsplit(const float* __restrict__ hse, ushort* __restrict__ hhi,
                         ushort* __restrict__ hlo) {
  int i = blockIdx.x * 256 + threadIdx.x;  // 16384 = 32*512
  int b = i >> 9, k = i & 511;
  float h = hse[(long)b * cNP1 * cH + k];
  ushort hi = f2bf(h);
  hhi[i] = hi;
  hlo[i] = f2bf(h - bf2f(hi));
}

// ---------------- one GRU step via MFMA (split-bf16, LDS-free, barrier-free) ----------------
// grid 32 (16-hh strips); block 128 (2 waves = m-tiles of batch dim)
// gh = Whi*hhi + Whi*hlo + Wlo*hhi  (f32 accum) -> fp32-grade
__global__ void __launch_bounds__(128) k_gru_mfma(
    const float* __restrict__ gi, const ushort* __restrict__ whi,
    const ushort* __restrict__ wlo, const float* __restrict__ b_hh,
    float* __restrict__ hse, const ushort* __restrict__ hhi_c,
    const ushort* __restrict__ hlo_c, ushort* __restrict__ hhi_n,
    ushort* __restrict__ hlo_n, int step) {
  int t = threadIdx.x;
  int w = t >> 6, lane = t & 63;
  int m0 = w * 16;                 // batch-tile base
  int hh0 = blockIdx.x * 16;       // hidden-col strip
  int r = lane & 15, q = lane >> 4;
  f32x4 acc[3];
#pragma unroll
  for (int g = 0; g < 3; ++g) acc[g] = (f32x4){0.f, 0.f, 0.f, 0.f};
  const ushort* ha = hhi_c + (long)(m0 + r) * cH;  // A-frag row (batch m0+r)
  const ushort* hb = hlo_c + (long)(m0 + r) * cH;
#pragma unroll 4
  for (int kc = 0; kc < 16; ++kc) {
    int k = kc * 32 + q * 8;
    bf16x8 ahi = *(const bf16x8*)(ha + k);
    bf16x8 alo = *(const bf16x8*)(hb + k);
#pragma unroll
    for (int g = 0; g < 3; ++g) {
      long bcol = (long)(g * cH + hh0 + r) * cH + k;
      bf16x8 bhi = *(const bf16x8*)(whi + bcol);
      bf16x8 blo = *(const bf16x8*)(wlo + bcol);
      acc[g] = __builtin_amdgcn_mfma_f32_16x16x32_bf16(ahi, bhi, acc[g], 0, 0, 0);
      acc[g] = __builtin_amdgcn_mfma_f32_16x16x32_bf16(alo, bhi, acc[g], 0, 0, 0);
      acc[g] = __builtin_amdgcn_mfma_f32_16x16x32_bf16(ahi, blo, acc[g], 0, 0, 0);
    }
  }
  // epilogue: lane holds (col hh0+r, rows m0+q*4+reg) for all 3 gates -> in-register
  int hh = hh0 + r;
  float bhr = b_hh[hh], bhz = b_hh[hh + cH], bhn = b_hh[hh + 2 * cH];
#pragma unroll
  for (int reg = 0; reg < 4; ++reg) {
    int b = m0 + q * 4 + reg;
    long girow = ((long)b * cN + step) * cH3;
    float rr = 1.f / (1.f + __expf(-(gi[girow + hh] + acc[0][reg] + bhr)));
    float zz = 1.f / (1.f + __expf(-(gi[girow + cH + hh] + acc[1][reg] + bhz)));
    float nn = tanhf(gi[girow + 2 * cH + hh] + rr * (acc[2][reg] + bhn));
    float hold = hse[((long)b * cNP1 + step) * cH + hh];
    float hnew = (1.f - zz) * nn + zz * hold;
    hse[((long)b * cNP1 + step + 1) * cH + hh] = hnew;
    ushort hi = f2bf(hnew);
    hhi_n[b * cH + hh] = hi;
    hlo_n[b * cH + hh] = f2bf(hnew - bf2f(hi));
  }
}

// ---------------- q partials: qp[kp][bn][col], k-split 2 ----------------
// grid (2 kp, 512 rowg); block 256; C=2, M=4
__global__ void __launch_bounds__(256, 4) k_qp(
    const float* __restrict__ hse, const float* __restrict__ W, float* __restrict__ qp) {
  __shared__ float4 s4[4 * 64];                    // 4 rows x 256-k slice (4 KB)
  int kp = blockIdx.x;
  int row0 = blockIdx.y * 4;
  int t = threadIdx.x;
  {
    int i = t;  // 256 entries, 1 per thread
    int m = i >> 6, k4 = i & 63;
    int bn = row0 + m;
    int b = bn >> 6, n = bn & 63;
    s4[i] = ((const float4*)(hse + ((long)b * cNP1 + 1 + n) * cH))[kp * 64 + k4];
  }
  __syncthreads();
  int col0 = t * 2;
  float2 acc[4];
#pragma unroll
  for (int m = 0; m < 4; ++m) acc[m] = make_float2(0.f, 0.f);
#pragma unroll 8
  for (int k4 = 0; k4 < 64; ++k4) {
    const float* wrow = W + (long)(kp * 256 + k4 * 4) * cH + col0;
    float2 w0 = *(const float2*)(wrow);
    float2 w1 = *(const float2*)(wrow + cH);
    float2 w2 = *(const float2*)(wrow + 2 * cH);
    float2 w3 = *(const float2*)(wrow + 3 * cH);
#pragma unroll
    for (int m = 0; m < 4; ++m) {
      float4 a = s4[m * 64 + k4];
      acc[m].x += a.x * w0.x + a.y * w1.x + a.z * w2.x + a.w * w3.x;
      acc[m].y += a.x * w0.y + a.y * w1.y + a.z * w2.y + a.w * w3.y;
    }
  }
#pragma unroll
  for (int m = 0; m < 4; ++m)
    *(float2*)(qp + ((long)kp * cBN + row0 + m) * cH + col0) = acc[m];
}

// ---------------- causal attention (q = qp0+qp1 folded into staging) ----------------
__global__ void k_attn(const float* __restrict__ qp, const float* __restrict__ hse,
                       float* __restrict__ c) {
  __shared__ float qs[cH];
  __shared__ float part[256];
  __shared__ float aw[cN];
  int bn = blockIdx.x;
  int b = bn >> 6, n = bn & 63;
  int t = threadIdx.x;
  const float* q0 = qp + (long)bn * cH;
  const float* q1 = qp + ((long)cBN + bn) * cH;
  qs[t] = q0[t] + q1[t];
  qs[t + 256] = q0[t + 256] + q1[t + 256];
  __syncthreads();
  int k = t & 63;
  int p = t >> 6;  // 4 partials per key
  const float* hrow = hse + ((long)b * cNP1 + 1 + k) * cH + p * 128;
  float s = 0.f;
#pragma unroll 8
  for (int j = 0; j < 128; ++j) s += qs[p * 128 + j] * hrow[j];
  part[t] = s;
  __syncthreads();
  if (t < 64) {
    float sc = part[t] + part[t + 64] + part[t + 128] + part[t + 192];
    if (t > n) sc = -1e30f;  // ref adds log(1e-45) ~ -103.6 -> exp underflows to 0
    float m = sc;
#pragma unroll
    for (int off = 32; off; off >>= 1) m = fmaxf(m, __shfl_xor(m, off));
    float e = __expf(sc - m);
    float sum = e;
#pragma unroll
    for (int off = 32; off; off >>= 1) sum += __shfl_xor(sum, off);
    aw[t] = e / sum;
  }
  __syncthreads();
  float c0 = 0.f, c1 = 0.f;
  for (int kk = 0; kk < cN; ++kk) {
    float a = aw[kk];
    const float* hr = hse + ((long)b * cNP1 + 1 + kk) * cH;
    c0 += a * hr[t];
    c1 += a * hr[t + 256];
  }
  c[(long)bn * cH + t] = c0;
  c[(long)bn * cH + t + 256] = c1;
}

// ---------------- cat[bn][0:1024] = bf16(concat(c[bn], hs[bn])) ----------------
__global__ void k_cat(const float* __restrict__ c, const float* __restrict__ hse,
                      ushort* __restrict__ cat) {
  int bn = blockIdx.x, t = threadIdx.x;
  int b = bn >> 6, n = bn & 63;
  float4 v = (t < 128) ? ((const float4*)(c + (long)bn * cH))[t]
                       : ((const float4*)(hse + ((long)b * cNP1 + 1 + n) * cH))[t - 128];
  ushort4 o;
  o.x = f2bf(v.x); o.y = f2bf(v.y); o.z = f2bf(v.z); o.w = f2bf(v.w);
  *(ushort4*)(cat + (long)bn * 1024 + t * 4) = o;
}

// ---------------- Bt[col][k] = bf16(W_att_out[k][col]) ----------------
// grid 256; block 256: 2 cols/block, 128 kgroups of 8
__global__ void k_bt(const float* __restrict__ W, ushort* __restrict__ Bt) {
  int t = threadIdx.x;
  int col = blockIdx.x * 2 + (t >> 7);
  int kg = t & 127;
  ushort u[8];
#pragma unroll
  for (int j = 0; j < 8; ++j) u[j] = f2bf(W[(long)(kg * 8 + j) * cH + col]);
  int4 o;
  o.x = (int)u[0] | ((int)u[1] << 16);
  o.y = (int)u[2] | ((int)u[3] << 16);
  o.z = (int)u[4] | ((int)u[5] << 16);
  o.w = (int)u[6] | ((int)u[7] << 16);
  *(int4*)(Bt + (long)col * 1024 + kg * 8) = o;
}

// ---------------- out = tanh(cat @ W_att_out + b) via MFMA bf16 ----------------
// grid (32 row-tiles, 8 col-tiles); block 256 (4 waves); tile 64x64, K=1024 in 16 chunks
__global__ void __launch_bounds__(256) k_out_mfma(
    const ushort* __restrict__ cat, const ushort* __restrict__ Bt,
    const float* __restrict__ bias, float* __restrict__ out) {
  __shared__ char lds[16384];  // A: [64 rows][64 k] bf16 swizzled; B at +8192 same
  int bn0 = blockIdx.x * 64, col0 = blockIdx.y * 64;
  int t = threadIdx.x;
  int w = t >> 6, lane = t & 63;
  f32x4 acc[4];
#pragma unroll
  for (int i = 0; i < 4; ++i) acc[i] = (f32x4){0.f, 0.f, 0.f, 0.f};
  int r = lane & 15, kg = lane >> 4;
  for (int kc = 0; kc < 16; ++kc) {
    int k0 = kc * 64;
#pragma unroll
    for (int p = 0; p < 2; ++p) {
      int i = t + p * 256;           // 0..511
      int row = i >> 3, ks = i & 7;  // 64 rows x 8 k-segments (8 bf16 = 16B)
      float4 va = *(const float4*)(cat + (long)(bn0 + row) * 1024 + k0 + ks * 8);
      *(float4*)(lds + ((row * 128 + ks * 16) ^ ((row & 7) << 4))) = va;
      float4 vb = *(const float4*)(Bt + (long)(col0 + row) * 1024 + k0 + ks * 8);
      *(float4*)(lds + 8192 + ((row * 128 + ks * 16) ^ ((row & 7) << 4))) = vb;
    }
    __syncthreads();
#pragma unroll
    for (int s = 0; s < 2; ++s) {
      int arow = w * 16 + r;
      bf16x8 a = *(const bf16x8*)(lds + ((arow * 128 + s * 64 + kg * 16) ^ ((arow & 7) << 4)));
#pragma unroll
      for (int cf = 0; cf < 4; ++cf) {
        int bcol = cf * 16 + r;
        bf16x8 bb = *(const bf16x8*)(lds + 8192 +
                                     ((bcol * 128 + s * 64 + kg * 16) ^ ((bcol & 7) << 4)));
        acc[cf] = __builtin_amdgcn_mfma_f32_16x16x32_bf16(a, bb, acc[cf], 0, 0, 0);
      }
    }
    __syncthreads();
  }
  int rq = lane >> 4;
#pragma unroll
  for (int cf = 0; cf < 4; ++cf) {
    int col = col0 + cf * 16 + r;
    float bv = bias[col];
#pragma unroll
    for (int reg = 0; reg < 4; ++reg) {
      int row = bn0 + w * 16 + rq * 4 + reg;
      out[(long)row * cH + col] = tanhf(acc[cf][reg] + bv);
    }
  }
}

extern "C" void kernel_launch(void* const* d_in, const int* in_sizes, int n_in,
                              void* d_out, int out_size, void* d_ws, size_t ws_size,
                              hipStream_t stream) {
  const int* sents = (const int*)d_in[0];
  const int* titles = (const int*)d_in[1];
  const float* emb = (const float*)d_in[2];
  const float* Wt = (const float*)d_in[3];
  const float* bt = (const float*)d_in[4];
  const float* W_ih = (const float*)d_in[5];
  const float* W_hh = (const float*)d_in[6];
  const float* b_ih = (const float*)d_in[7];
  const float* b_hh = (const float*)d_in[8];
  const float* W_att_in = (const float*)d_in[9];
  const float* W_att_out = (const float*)d_in[10];
  const float* b_att_out = (const float*)d_in[11];
  float* out = (float*)d_out;

  float* ws = (float*)d_ws;
  float* x = ws;                                   // BN*D
  float* tsum = x + (long)cBN * cD;                // B*D
  float* gi = tsum + (long)cB * cD;                // BN*3H (live through scan)
  float* hse = gi + (long)cBN * cH3;               // B*65*H
  float* c = hse + (long)cB * cNP1 * cH;           // BN*H
  ushort* whi = (ushort*)(c + (long)cBN * cH);     // 1536*512 bf16 (1.5 MB)
  ushort* wlo = whi + 1536 * 512;                  // 1.5 MB
  ushort* h0hi = wlo + 1536 * 512;                 // 32*512 parity buffers
  ushort* h0lo = h0hi + cB * cH;
  ushort* h1hi = h0lo + cB * cH;
  ushort* h1lo = h1hi + cB * cH;
  float* qp = gi;                                  // q-partials alias dead gi... (dead AFTER scan)
  ushort* catb = (ushort*)gi;                      // alias gi after k_attn
  ushort* Btb = catb + (long)cBN * 1024;           // 1 MB

  k_embed_x<<<cBN, 256, 0, stream>>>(sents, emb, x);
  k_title<<<cB, 256, 0, stream>>>(titles, emb, tsum);
  k_h0<<<(cB * cH) / 256, 256, 0, stream>>>(tsum, Wt, bt, hse);
  k_gi<<<dim3(3, cBN / 4), 128, 0, stream>>>(x, W_ih, b_ih, gi);
  k_whhsplit<<<dim3(24, 8), 256, 0, stream>>>(W_hh, whi, wlo);
  k_hsplit<<<64, 256, 0, stream>>>(hse, h0hi, h0lo);
  for (int step = 0; step < cN; ++step) {
    const ushort* chi = (step & 1) ? h1hi : h0hi;
    const ushort* clo = (step & 1) ? h1lo : h0lo;
    ushort* nhi = (step & 1) ? h0hi : h1hi;
    ushort* nlo = (step & 1) ? h0lo : h1lo;
    k_gru_mfma<<<32, 128, 0, stream>>>(gi, whi, wlo, b_hh, hse, chi, clo, nhi, nlo, step);
  }
  k_qp<<<dim3(2, cBN / 4), 256, 0, stream>>>(hse, W_att_in, qp);
  k_attn<<<cBN, 256, 0, stream>>>(qp, hse, c);
  k_bt<<<256, 256, 0, stream>>>(W_att_out, Btb);
  k_cat<<<cBN, 256, 0, stream>>>(c, hse, catb);
  k_out_mfma<<<dim3(32, 8), 256, 0, stream>>>(catb, Btb, b_att_out, out);
}

// Round 17
// 498.864 us; speedup vs baseline: 1.9655x; 1.9655x over previous
//
#include <hip/hip_runtime.h>
#include <hip/hip_bf16.h>

constexpr int cB = 32, cN = 64, cL = 64, cT = 10, cD = 256, cH = 512, cH3 = 1536;
constexpr int cBN = cB * cN;   // 2048
constexpr int cNP1 = cN + 1;   // 65: hidden tape, slot 0 = h0, slot n+1 = hs[:,n,:]

typedef __bf16 bf16x8 __attribute__((ext_vector_type(8)));
typedef float f32x4 __attribute__((ext_vector_type(4)));

__device__ __forceinline__ ushort f2bf(float f) {
  __hip_bfloat16 h = __float2bfloat16(f);
  return *reinterpret_cast<ushort*>(&h);
}

// ---------------- x[bn][d] = sum_l emb[sents[bn][l]][d] ----------------
__global__ void k_embed_x(const int* __restrict__ sents, const float* __restrict__ emb,
                          float* __restrict__ x) {
  __shared__ int idx[cL];
  int bn = blockIdx.x, t = threadIdx.x;
  if (t < cL) idx[t] = sents[bn * cL + t];
  __syncthreads();
  float acc = 0.f;
#pragma unroll 8
  for (int l = 0; l < cL; ++l) acc += emb[(long)idx[l] * cD + t];
  x[bn * cD + t] = acc;
}

// ---------------- tsum[b][d] = sum_t emb[titles[b][0][t]][d] ----------------
__global__ void k_title(const int* __restrict__ titles, const float* __restrict__ emb,
                        float* __restrict__ tsum) {
  __shared__ int idx[cT];
  int b = blockIdx.x, t = threadIdx.x;
  if (t < cT) idx[t] = titles[b * cN * cT + t];
  __syncthreads();
  float acc = 0.f;
#pragma unroll
  for (int i = 0; i < cT; ++i) acc += emb[(long)idx[i] * cD + t];
  tsum[b * cD + t] = acc;
}

// ---------------- h0 = tsum @ Wt + bt -> hse slot 0 ----------------
__global__ void k_h0(const float* __restrict__ tsum, const float* __restrict__ Wt,
                     const float* __restrict__ bt, float* __restrict__ hse) {
  int i = blockIdx.x * blockDim.x + threadIdx.x;  // B*H
  int b = i >> 9, hh = i & (cH - 1);
  const float* ts = tsum + b * cD;
  float acc = bt[hh];
  for (int k = 0; k < cD; ++k) acc += ts[k] * Wt[(long)k * cH + hh];
  hse[(long)b * cNP1 * cH + hh] = acc;
}

// ---------------- x -> bf16 ----------------
__global__ void k_xcast(const float* __restrict__ x, ushort* __restrict__ xb) {
  int bn = blockIdx.x, t = threadIdx.x;  // 64 threads, 4 elems each
  float4 v = ((const float4*)(x + (long)bn * cD))[t];
  ushort4 o;
  o.x = f2bf(v.x); o.y = f2bf(v.y); o.z = f2bf(v.z); o.w = f2bf(v.w);
  *(ushort4*)(xb + (long)bn * cD + t * 4) = o;
}

// ---------------- W_ih -> transposed bf16: bti[col][k] ----------------
// grid (24 colg, 4 kg); block 256; LDS-tiled transpose
__global__ void k_bti(const float* __restrict__ W, ushort* __restrict__ Bt) {
  __shared__ float tile[64][65];
  int col0 = blockIdx.x * 64, k0 = blockIdx.y * 64;
  int t = threadIdx.x;
  for (int i = t; i < 4096; i += 256) {
    int kr = i >> 6, cc = i & 63;
    tile[kr][cc] = W[(long)(k0 + kr) * cH3 + col0 + cc];
  }
  __syncthreads();
  for (int i = t; i < 4096; i += 256) {
    int cc = i >> 6, kr = i & 63;
    Bt[(long)(col0 + cc) * cD + k0 + kr] = f2bf(tile[kr][cc]);
  }
}

// ---------------- W_att_in -> transposed bf16: bq[col][k] ----------------
// grid (8 colg, 8 kg); block 256
__global__ void k_bq(const float* __restrict__ W, ushort* __restrict__ Bt) {
  __shared__ float tile[64][65];
  int col0 = blockIdx.x * 64, k0 = blockIdx.y * 64;
  int t = threadIdx.x;
  for (int i = t; i < 4096; i += 256) {
    int kr = i >> 6, cc = i & 63;
    tile[kr][cc] = W[(long)(k0 + kr) * cH + col0 + cc];
  }
  __syncthreads();
  for (int i = t; i < 4096; i += 256) {
    int cc = i >> 6, kr = i & 63;
    Bt[(long)(col0 + cc) * cH + k0 + kr] = f2bf(tile[kr][cc]);
  }
}

// ---------------- GI = X @ W_ih + b_ih via MFMA ----------------
// grid (32 row-tiles, 24 col-tiles); block 256 (4 waves); tile 64x64, K=256 (4 chunks)
__global__ void __launch_bounds__(256) k_gi_mfma(
    const ushort* __restrict__ xb, const ushort* __restrict__ Bt,
    const float* __restrict__ b_ih, float* __restrict__ gi) {
  __shared__ char lds[16384];
  int bn0 = blockIdx.x * 64, col0 = blockIdx.y * 64;
  int t = threadIdx.x;
  int w = t >> 6, lane = t & 63;
  f32x4 acc[4];
#pragma unroll
  for (int i = 0; i < 4; ++i) acc[i] = (f32x4){0.f, 0.f, 0.f, 0.f};
  int r = lane & 15, kg = lane >> 4;
  for (int kc = 0; kc < 4; ++kc) {
    int k0 = kc * 64;
#pragma unroll
    for (int p = 0; p < 2; ++p) {
      int i = t + p * 256;
      int row = i >> 3, ks = i & 7;
      float4 va = *(const float4*)(xb + (long)(bn0 + row) * cD + k0 + ks * 8);
      *(float4*)(lds + ((row * 128 + ks * 16) ^ ((row & 7) << 4))) = va;
      float4 vb = *(const float4*)(Bt + (long)(col0 + row) * cD + k0 + ks * 8);
      *(float4*)(lds + 8192 + ((row * 128 + ks * 16) ^ ((row & 7) << 4))) = vb;
    }
    __syncthreads();
#pragma unroll
    for (int s = 0; s < 2; ++s) {
      int arow = w * 16 + r;
      bf16x8 a = *(const bf16x8*)(lds + ((arow * 128 + s * 64 + kg * 16) ^ ((arow & 7) << 4)));
#pragma unroll
      for (int cf = 0; cf < 4; ++cf) {
        int bcol = cf * 16 + r;
        bf16x8 bb = *(const bf16x8*)(lds + 8192 +
                                     ((bcol * 128 + s * 64 + kg * 16) ^ ((bcol & 7) << 4)));
        acc[cf] = __builtin_amdgcn_mfma_f32_16x16x32_bf16(a, bb, acc[cf], 0, 0, 0);
      }
    }
    __syncthreads();
  }
  int rq = lane >> 4;
#pragma unroll
  for (int cf = 0; cf < 4; ++cf) {
    int col = col0 + cf * 16 + r;
    float bv = b_ih[col];
#pragma unroll
    for (int reg = 0; reg < 4; ++reg) {
      int row = bn0 + w * 16 + rq * 4 + reg;
      gi[(long)row * cH3 + col] = acc[cf][reg] + bv;
    }
  }
}

// ---------------- one GRU step (v5: f32, no h-stage, ONE barrier; r15-proven) ----------------
// grid 256 = bg(8: 4 batches) x cg(32: 16 cols/gate); block 512
__global__ void __launch_bounds__(512, 1) k_gru_step(
    const float* __restrict__ gi, const float* __restrict__ W_hh,
    const float* __restrict__ b_hh, float* __restrict__ hse, int step) {
  __shared__ float part[512][13];
  int cg = blockIdx.x & 31;
  int bg = blockIdx.x >> 5;
  int t = threadIdx.x;

  float ir = 0.f, iz = 0.f, in_ = 0.f, bhr = 0.f, bhz = 0.f, bhn = 0.f, hold = 0.f;
  int e_bl = (t >> 4) & 3, e_cl = t & 15;
  if (t < 64) {
    int bb = bg * 4 + e_bl;
    int hh = cg * 16 + e_cl;
    long girow = ((long)bb * cN + step) * cH3;
    ir = gi[girow + hh];
    iz = gi[girow + hh + cH];
    in_ = gi[girow + hh + 2 * cH];
    bhr = b_hh[hh];
    bhz = b_hh[hh + cH];
    bhn = b_hh[hh + 2 * cH];
    hold = hse[((long)bb * cNP1 + step) * cH + hh];
  }

  int c4 = t & 3, b = (t >> 2) & 3, kp = t >> 4;
  int col0 = cg * 16 + c4 * 4;
  const float* hrow = hse + ((long)(bg * 4 + b) * cNP1 + step) * cH;
  int k0 = kp * 16;
  float4 h0 = *(const float4*)(hrow + k0);
  float4 h1 = *(const float4*)(hrow + k0 + 4);
  float4 h2 = *(const float4*)(hrow + k0 + 8);
  float4 h3 = *(const float4*)(hrow + k0 + 12);
  float ar[4] = {0, 0, 0, 0}, az[4] = {0, 0, 0, 0}, an[4] = {0, 0, 0, 0};
#define GRU_K(HV, KOFF)                                                         \
  {                                                                             \
    const float* wp = W_hh + (long)(k0 + (KOFF)) * cH3 + col0;                  \
    float4 wr = *(const float4*)(wp);                                           \
    float4 wz = *(const float4*)(wp + cH);                                      \
    float4 wn = *(const float4*)(wp + 2 * cH);                                  \
    ar[0] += (HV)*wr.x; ar[1] += (HV)*wr.y; ar[2] += (HV)*wr.z; ar[3] += (HV)*wr.w; \
    az[0] += (HV)*wz.x; az[1] += (HV)*wz.y; az[2] += (HV)*wz.z; az[3] += (HV)*wz.w; \
    an[0] += (HV)*wn.x; an[1] += (HV)*wn.y; an[2] += (HV)*wn.z; an[3] += (HV)*wn.w; \
  }
  GRU_K(h0.x, 0) GRU_K(h0.y, 1) GRU_K(h0.z, 2) GRU_K(h0.w, 3)
  GRU_K(h1.x, 4) GRU_K(h1.y, 5) GRU_K(h1.z, 6) GRU_K(h1.w, 7)
  GRU_K(h2.x, 8) GRU_K(h2.y, 9) GRU_K(h2.z, 10) GRU_K(h2.w, 11)
  GRU_K(h3.x, 12) GRU_K(h3.y, 13) GRU_K(h3.z, 14) GRU_K(h3.w, 15)
#undef GRU_K
#pragma unroll
  for (int j = 0; j < 4; ++j) {
    part[t][j] = ar[j];
    part[t][4 + j] = az[j];
    part[t][8 + j] = an[j];
  }
  __syncthreads();
  if (t < 64) {
    int c4f = e_cl >> 2, jf = e_cl & 3;
    float sr = 0.f, sz = 0.f, sn = 0.f;
#pragma unroll
    for (int p = 0; p < 32; ++p) {
      const float* pp = part[p * 16 + e_bl * 4 + c4f];
      sr += pp[jf];
      sz += pp[4 + jf];
      sn += pp[8 + jf];
    }
    int bb = bg * 4 + e_bl;
    int hh = cg * 16 + e_cl;
    float rr = 1.f / (1.f + __expf(-(ir + sr + bhr)));
    float zz = 1.f / (1.f + __expf(-(iz + sz + bhz)));
    float nn = tanhf(in_ + rr * (sn + bhn));
    hse[((long)bb * cNP1 + step + 1) * cH + hh] = (1.f - zz) * nn + zz * hold;
  }
}

// ---------------- hs -> bf16: hsb[bn][k] ----------------
__global__ void k_hscast(const float* __restrict__ hse, ushort* __restrict__ hsb) {
  int bn = blockIdx.x, t = threadIdx.x;  // 128 threads x float4
  int b = bn >> 6, n = bn & 63;
  float4 v = ((const float4*)(hse + ((long)b * cNP1 + 1 + n) * cH))[t];
  ushort4 o;
  o.x = f2bf(v.x); o.y = f2bf(v.y); o.z = f2bf(v.z); o.w = f2bf(v.w);
  *(ushort4*)(hsb + (long)bn * cH + t * 4) = o;
}

// ---------------- q = hs @ W_att_in via MFMA ----------------
// grid (32 row-tiles, 8 col-tiles); block 256 (4 waves); tile 64x64, K=512 (8 chunks)
__global__ void __launch_bounds__(256) k_q_mfma(
    const ushort* __restrict__ hsb, const ushort* __restrict__ Bt,
    float* __restrict__ q) {
  __shared__ char lds[16384];
  int bn0 = blockIdx.x * 64, col0 = blockIdx.y * 64;
  int t = threadIdx.x;
  int w = t >> 6, lane = t & 63;
  f32x4 acc[4];
#pragma unroll
  for (int i = 0; i < 4; ++i) acc[i] = (f32x4){0.f, 0.f, 0.f, 0.f};
  int r = lane & 15, kg = lane >> 4;
  for (int kc = 0; kc < 8; ++kc) {
    int k0 = kc * 64;
#pragma unroll
    for (int p = 0; p < 2; ++p) {
      int i = t + p * 256;
      int row = i >> 3, ks = i & 7;
      float4 va = *(const float4*)(hsb + (long)(bn0 + row) * cH + k0 + ks * 8);
      *(float4*)(lds + ((row * 128 + ks * 16) ^ ((row & 7) << 4))) = va;
      float4 vb = *(const float4*)(Bt + (long)(col0 + row) * cH + k0 + ks * 8);
      *(float4*)(lds + 8192 + ((row * 128 + ks * 16) ^ ((row & 7) << 4))) = vb;
    }
    __syncthreads();
#pragma unroll
    for (int s = 0; s < 2; ++s) {
      int arow = w * 16 + r;
      bf16x8 a = *(const bf16x8*)(lds + ((arow * 128 + s * 64 + kg * 16) ^ ((arow & 7) << 4)));
#pragma unroll
      for (int cf = 0; cf < 4; ++cf) {
        int bcol = cf * 16 + r;
        bf16x8 bb = *(const bf16x8*)(lds + 8192 +
                                     ((bcol * 128 + s * 64 + kg * 16) ^ ((bcol & 7) << 4)));
        acc[cf] = __builtin_amdgcn_mfma_f32_16x16x32_bf16(a, bb, acc[cf], 0, 0, 0);
      }
    }
    __syncthreads();
  }
  int rq = lane >> 4;
#pragma unroll
  for (int cf = 0; cf < 4; ++cf) {
    int col = col0 + cf * 16 + r;
#pragma unroll
    for (int reg = 0; reg < 4; ++reg) {
      int row = bn0 + w * 16 + rq * 4 + reg;
      q[(long)row * cH + col] = acc[cf][reg];
    }
  }
}

// ---------------- causal attention (plain q) ----------------
__global__ void k_attn(const float* __restrict__ q, const float* __restrict__ hse,
                       float* __restrict__ c) {
  __shared__ float qs[cH];
  __shared__ float part[256];
  __shared__ float aw[cN];
  int bn = blockIdx.x;
  int b = bn >> 6, n = bn & 63;
  int t = threadIdx.x;
  qs[t] = q[(long)bn * cH + t];
  qs[t + 256] = q[(long)bn * cH + t + 256];
  __syncthreads();
  int k = t & 63;
  int p = t >> 6;  // 4 partials per key
  const float* hrow = hse + ((long)b * cNP1 + 1 + k) * cH + p * 128;
  float s = 0.f;
#pragma unroll 8
  for (int j = 0; j < 128; ++j) s += qs[p * 128 + j] * hrow[j];
  part[t] = s;
  __syncthreads();
  if (t < 64) {
    float sc = part[t] + part[t + 64] + part[t + 128] + part[t + 192];
    if (t > n) sc = -1e30f;  // ref adds log(1e-45) ~ -103.6 -> exp underflows to 0
    float m = sc;
#pragma unroll
    for (int off = 32; off; off >>= 1) m = fmaxf(m, __shfl_xor(m, off));
    float e = __expf(sc - m);
    float sum = e;
#pragma unroll
    for (int off = 32; off; off >>= 1) sum += __shfl_xor(sum, off);
    aw[t] = e / sum;
  }
  __syncthreads();
  float c0 = 0.f, c1 = 0.f;
  for (int kk = 0; kk < cN; ++kk) {
    float a = aw[kk];
    const float* hr = hse + ((long)b * cNP1 + 1 + kk) * cH;
    c0 += a * hr[t];
    c1 += a * hr[t + 256];
  }
  c[(long)bn * cH + t] = c0;
  c[(long)bn * cH + t + 256] = c1;
}

// ---------------- cat[bn][0:1024] = bf16(concat(c[bn], hs[bn])) ----------------
__global__ void k_cat(const float* __restrict__ c, const float* __restrict__ hse,
                      ushort* __restrict__ cat) {
  int bn = blockIdx.x, t = threadIdx.x;
  int b = bn >> 6, n = bn & 63;
  float4 v = (t < 128) ? ((const float4*)(c + (long)bn * cH))[t]
                       : ((const float4*)(hse + ((long)b * cNP1 + 1 + n) * cH))[t - 128];
  ushort4 o;
  o.x = f2bf(v.x); o.y = f2bf(v.y); o.z = f2bf(v.z); o.w = f2bf(v.w);
  *(ushort4*)(cat + (long)bn * 1024 + t * 4) = o;
}

// ---------------- Bt[col][k] = bf16(W_att_out[k][col]) ----------------
__global__ void k_bt(const float* __restrict__ W, ushort* __restrict__ Bt) {
  int t = threadIdx.x;
  int col = blockIdx.x * 2 + (t >> 7);
  int kg = t & 127;
  ushort u[8];
#pragma unroll
  for (int j = 0; j < 8; ++j) u[j] = f2bf(W[(long)(kg * 8 + j) * cH + col]);
  int4 o;
  o.x = (int)u[0] | ((int)u[1] << 16);
  o.y = (int)u[2] | ((int)u[3] << 16);
  o.z = (int)u[4] | ((int)u[5] << 16);
  o.w = (int)u[6] | ((int)u[7] << 16);
  *(int4*)(Bt + (long)col * 1024 + kg * 8) = o;
}

// ---------------- out = tanh(cat @ W_att_out + b) via MFMA bf16 ----------------
// grid (32 row-tiles, 8 col-tiles); block 256 (4 waves); tile 64x64, K=1024 (16 chunks)
__global__ void __launch_bounds__(256) k_out_mfma(
    const ushort* __restrict__ cat, const ushort* __restrict__ Bt,
    const float* __restrict__ bias, float* __restrict__ out) {
  __shared__ char lds[16384];
  int bn0 = blockIdx.x * 64, col0 = blockIdx.y * 64;
  int t = threadIdx.x;
  int w = t >> 6, lane = t & 63;
  f32x4 acc[4];
#pragma unroll
  for (int i = 0; i < 4; ++i) acc[i] = (f32x4){0.f, 0.f, 0.f, 0.f};
  int r = lane & 15, kg = lane >> 4;
  for (int kc = 0; kc < 16; ++kc) {
    int k0 = kc * 64;
#pragma unroll
    for (int p = 0; p < 2; ++p) {
      int i = t + p * 256;
      int row = i >> 3, ks = i & 7;
      float4 va = *(const float4*)(cat + (long)(bn0 + row) * 1024 + k0 + ks * 8);
      *(float4*)(lds + ((row * 128 + ks * 16) ^ ((row & 7) << 4))) = va;
      float4 vb = *(const float4*)(Bt + (long)(col0 + row) * 1024 + k0 + ks * 8);
      *(float4*)(lds + 8192 + ((row * 128 + ks * 16) ^ ((row & 7) << 4))) = vb;
    }
    __syncthreads();
#pragma unroll
    for (int s = 0; s < 2; ++s) {
      int arow = w * 16 + r;
      bf16x8 a = *(const bf16x8*)(lds + ((arow * 128 + s * 64 + kg * 16) ^ ((arow & 7) << 4)));
#pragma unroll
      for (int cf = 0; cf < 4; ++cf) {
        int bcol = cf * 16 + r;
        bf16x8 bb = *(const bf16x8*)(lds + 8192 +
                                     ((bcol * 128 + s * 64 + kg * 16) ^ ((bcol & 7) << 4)));
        acc[cf] = __builtin_amdgcn_mfma_f32_16x16x32_bf16(a, bb, acc[cf], 0, 0, 0);
      }
    }
    __syncthreads();
  }
  int rq = lane >> 4;
#pragma unroll
  for (int cf = 0; cf < 4; ++cf) {
    int col = col0 + cf * 16 + r;
    float bv = bias[col];
#pragma unroll
    for (int reg = 0; reg < 4; ++reg) {
      int row = bn0 + w * 16 + rq * 4 + reg;
      out[(long)row * cH + col] = tanhf(acc[cf][reg] + bv);
    }
  }
}

extern "C" void kernel_launch(void* const* d_in, const int* in_sizes, int n_in,
                              void* d_out, int out_size, void* d_ws, size_t ws_size,
                              hipStream_t stream) {
  const int* sents = (const int*)d_in[0];
  const int* titles = (const int*)d_in[1];
  const float* emb = (const float*)d_in[2];
  const float* Wt = (const float*)d_in[3];
  const float* bt = (const float*)d_in[4];
  const float* W_ih = (const float*)d_in[5];
  const float* W_hh = (const float*)d_in[6];
  const float* b_ih = (const float*)d_in[7];
  const float* b_hh = (const float*)d_in[8];
  const float* W_att_in = (const float*)d_in[9];
  const float* W_att_out = (const float*)d_in[10];
  const float* b_att_out = (const float*)d_in[11];
  float* out = (float*)d_out;

  float* ws = (float*)d_ws;
  float* x = ws;                                   // BN*D f32 (2 MB)
  float* tsum = x + (long)cBN * cD;                // B*D
  float* gi = tsum + (long)cB * cD;                // BN*3H f32 (12.6 MB, live through scan)
  float* hse = gi + (long)cBN * cH3;               // B*65*H f32 (8.5 MB)
  float* c = hse + (long)cB * cNP1 * cH;           // BN*H f32 (4.2 MB)
  // tail (precomputable, proven-size region from r16): xb | bti | bq
  ushort* xb = (ushort*)(c + (long)cBN * cH);      // 2048*256 bf16 (1 MB)
  ushort* bti = xb + (long)cBN * cD;               // 1536*256 bf16 (0.75 MB)
  ushort* bq = bti + (long)cH3 * cD;               // 512*512 bf16 (0.5 MB)
  // dead-gi aliases (after scan): q | catb | Btb | hsb  (11.4 < 12.6 MB)
  float* q = gi;
  ushort* catb = (ushort*)(gi + (long)cBN * cH);
  ushort* Btb = catb + (long)cBN * 1024;
  ushort* hsb = Btb + (long)cH * 1024;

  k_embed_x<<<cBN, 256, 0, stream>>>(sents, emb, x);
  k_title<<<cB, 256, 0, stream>>>(titles, emb, tsum);
  k_h0<<<(cB * cH) / 256, 256, 0, stream>>>(tsum, Wt, bt, hse);
  k_xcast<<<cBN, 64, 0, stream>>>(x, xb);
  k_bti<<<dim3(24, 4), 256, 0, stream>>>(W_ih, bti);
  k_bq<<<dim3(8, 8), 256, 0, stream>>>(W_att_in, bq);
  k_gi_mfma<<<dim3(32, 24), 256, 0, stream>>>(xb, bti, b_ih, gi);
  for (int step = 0; step < cN; ++step)
    k_gru_step<<<256, 512, 0, stream>>>(gi, W_hh, b_hh, hse, step);
  k_hscast<<<cBN, 128, 0, stream>>>(hse, hsb);
  k_q_mfma<<<dim3(32, 8), 256, 0, stream>>>(hsb, bq, q);
  k_attn<<<cBN, 256, 0, stream>>>(q, hse, c);
  k_bt<<<256, 256, 0, stream>>>(W_att_out, Btb);
  k_cat<<<cBN, 256, 0, stream>>>(c, hse, catb);
  k_out_mfma<<<dim3(32, 8), 256, 0, stream>>>(catb, Btb, b_att_out, out);
}

// Round 18
// 461.740 us; speedup vs baseline: 2.1236x; 1.0804x over previous
//
#include <hip/hip_runtime.h>
#include <hip/hip_bf16.h>

constexpr int cB = 32, cN = 64, cL = 64, cT = 10, cD = 256, cH = 512, cH3 = 1536;
constexpr int cBN = cB * cN;   // 2048
constexpr int cNP1 = cN + 1;   // 65: hidden tape, slot 0 = h0, slot n+1 = hs[:,n,:]

typedef __bf16 bf16x8 __attribute__((ext_vector_type(8)));
typedef float f32x4 __attribute__((ext_vector_type(4)));

__device__ __forceinline__ ushort f2bf(float f) {
  __hip_bfloat16 h = __float2bfloat16(f);
  return *reinterpret_cast<ushort*>(&h);
}

// ---------------- xb[bn][d] = bf16( sum_l emb[sents[bn][l]][d] ) ----------------
__global__ void k_embed_x(const int* __restrict__ sents, const float* __restrict__ emb,
                          ushort* __restrict__ xb) {
  __shared__ int idx[cL];
  int bn = blockIdx.x, t = threadIdx.x;
  if (t < cL) idx[t] = sents[bn * cL + t];
  __syncthreads();
  float acc = 0.f;
#pragma unroll 8
  for (int l = 0; l < cL; ++l) acc += emb[(long)idx[l] * cD + t];
  xb[bn * cD + t] = f2bf(acc);
}

// ---------------- tsum[b][d] = sum_t emb[titles[b][0][t]][d] ----------------
__global__ void k_title(const int* __restrict__ titles, const float* __restrict__ emb,
                        float* __restrict__ tsum) {
  __shared__ int idx[cT];
  int b = blockIdx.x, t = threadIdx.x;
  if (t < cT) idx[t] = titles[b * cN * cT + t];
  __syncthreads();
  float acc = 0.f;
#pragma unroll
  for (int i = 0; i < cT; ++i) acc += emb[(long)idx[i] * cD + t];
  tsum[b * cD + t] = acc;
}

// ---------------- h0 = tsum @ Wt + bt -> hse slot 0 ----------------
__global__ void k_h0(const float* __restrict__ tsum, const float* __restrict__ Wt,
                     const float* __restrict__ bt, float* __restrict__ hse) {
  int i = blockIdx.x * blockDim.x + threadIdx.x;  // B*H
  int b = i >> 9, hh = i & (cH - 1);
  const float* ts = tsum + b * cD;
  float acc = bt[hh];
  for (int k = 0; k < cD; ++k) acc += ts[k] * Wt[(long)k * cH + hh];
  hse[(long)b * cNP1 * cH + hh] = acc;
}

// ---------------- W_ih -> transposed bf16: bti[col][k] ----------------
__global__ void k_bti(const float* __restrict__ W, ushort* __restrict__ Bt) {
  __shared__ float tile[64][65];
  int col0 = blockIdx.x * 64, k0 = blockIdx.y * 64;
  int t = threadIdx.x;
  for (int i = t; i < 4096; i += 256) {
    int kr = i >> 6, cc = i & 63;
    tile[kr][cc] = W[(long)(k0 + kr) * cH3 + col0 + cc];
  }
  __syncthreads();
  for (int i = t; i < 4096; i += 256) {
    int cc = i >> 6, kr = i & 63;
    Bt[(long)(col0 + cc) * cD + k0 + kr] = f2bf(tile[kr][cc]);
  }
}

// ---------------- W_att_in -> transposed bf16: bq[col][k] ----------------
__global__ void k_bq(const float* __restrict__ W, ushort* __restrict__ Bt) {
  __shared__ float tile[64][65];
  int col0 = blockIdx.x * 64, k0 = blockIdx.y * 64;
  int t = threadIdx.x;
  for (int i = t; i < 4096; i += 256) {
    int kr = i >> 6, cc = i & 63;
    tile[kr][cc] = W[(long)(k0 + kr) * cH + col0 + cc];
  }
  __syncthreads();
  for (int i = t; i < 4096; i += 256) {
    int cc = i >> 6, kr = i & 63;
    Bt[(long)(col0 + cc) * cH + k0 + kr] = f2bf(tile[kr][cc]);
  }
}

// ---------------- GI = X @ W_ih + b_ih via MFMA ----------------
// grid (32 row-tiles, 24 col-tiles); block 256 (4 waves); tile 64x64, K=256 (4 chunks)
__global__ void __launch_bounds__(256) k_gi_mfma(
    const ushort* __restrict__ xb, const ushort* __restrict__ Bt,
    const float* __restrict__ b_ih, float* __restrict__ gi) {
  __shared__ char lds[16384];
  int bn0 = blockIdx.x * 64, col0 = blockIdx.y * 64;
  int t = threadIdx.x;
  int w = t >> 6, lane = t & 63;
  f32x4 acc[4];
#pragma unroll
  for (int i = 0; i < 4; ++i) acc[i] = (f32x4){0.f, 0.f, 0.f, 0.f};
  int r = lane & 15, kg = lane >> 4;
  for (int kc = 0; kc < 4; ++kc) {
    int k0 = kc * 64;
#pragma unroll
    for (int p = 0; p < 2; ++p) {
      int i = t + p * 256;
      int row = i >> 3, ks = i & 7;
      float4 va = *(const float4*)(xb + (long)(bn0 + row) * cD + k0 + ks * 8);
      *(float4*)(lds + ((row * 128 + ks * 16) ^ ((row & 7) << 4))) = va;
      float4 vb = *(const float4*)(Bt + (long)(col0 + row) * cD + k0 + ks * 8);
      *(float4*)(lds + 8192 + ((row * 128 + ks * 16) ^ ((row & 7) << 4))) = vb;
    }
    __syncthreads();
#pragma unroll
    for (int s = 0; s < 2; ++s) {
      int arow = w * 16 + r;
      bf16x8 a = *(const bf16x8*)(lds + ((arow * 128 + s * 64 + kg * 16) ^ ((arow & 7) << 4)));
#pragma unroll
      for (int cf = 0; cf < 4; ++cf) {
        int bcol = cf * 16 + r;
        bf16x8 bb = *(const bf16x8*)(lds + 8192 +
                                     ((bcol * 128 + s * 64 + kg * 16) ^ ((bcol & 7) << 4)));
        acc[cf] = __builtin_amdgcn_mfma_f32_16x16x32_bf16(a, bb, acc[cf], 0, 0, 0);
      }
    }
    __syncthreads();
  }
  int rq = lane >> 4;
#pragma unroll
  for (int cf = 0; cf < 4; ++cf) {
    int col = col0 + cf * 16 + r;
    float bv = b_ih[col];
#pragma unroll
    for (int reg = 0; reg < 4; ++reg) {
      int row = bn0 + w * 16 + rq * 4 + reg;
      gi[(long)row * cH3 + col] = acc[cf][reg] + bv;
    }
  }
}

// ---------------- one GRU step (v5: f32, no h-stage, ONE barrier; proven) ----------------
// grid 256 = bg(8: 4 batches) x cg(32: 16 cols/gate); block 512
__global__ void __launch_bounds__(512, 1) k_gru_step(
    const float* __restrict__ gi, const float* __restrict__ W_hh,
    const float* __restrict__ b_hh, float* __restrict__ hse, int step) {
  __shared__ float part[512][13];
  int cg = blockIdx.x & 31;
  int bg = blockIdx.x >> 5;
  int t = threadIdx.x;

  float ir = 0.f, iz = 0.f, in_ = 0.f, bhr = 0.f, bhz = 0.f, bhn = 0.f, hold = 0.f;
  int e_bl = (t >> 4) & 3, e_cl = t & 15;
  if (t < 64) {
    int bb = bg * 4 + e_bl;
    int hh = cg * 16 + e_cl;
    long girow = ((long)bb * cN + step) * cH3;
    ir = gi[girow + hh];
    iz = gi[girow + hh + cH];
    in_ = gi[girow + hh + 2 * cH];
    bhr = b_hh[hh];
    bhz = b_hh[hh + cH];
    bhn = b_hh[hh + 2 * cH];
    hold = hse[((long)bb * cNP1 + step) * cH + hh];
  }

  int c4 = t & 3, b = (t >> 2) & 3, kp = t >> 4;
  int col0 = cg * 16 + c4 * 4;
  const float* hrow = hse + ((long)(bg * 4 + b) * cNP1 + step) * cH;
  int k0 = kp * 16;
  float4 h0 = *(const float4*)(hrow + k0);
  float4 h1 = *(const float4*)(hrow + k0 + 4);
  float4 h2 = *(const float4*)(hrow + k0 + 8);
  float4 h3 = *(const float4*)(hrow + k0 + 12);
  float ar[4] = {0, 0, 0, 0}, az[4] = {0, 0, 0, 0}, an[4] = {0, 0, 0, 0};
#define GRU_K(HV, KOFF)                                                         \
  {                                                                             \
    const float* wp = W_hh + (long)(k0 + (KOFF)) * cH3 + col0;                  \
    float4 wr = *(const float4*)(wp);                                           \
    float4 wz = *(const float4*)(wp + cH);                                      \
    float4 wn = *(const float4*)(wp + 2 * cH);                                  \
    ar[0] += (HV)*wr.x; ar[1] += (HV)*wr.y; ar[2] += (HV)*wr.z; ar[3] += (HV)*wr.w; \
    az[0] += (HV)*wz.x; az[1] += (HV)*wz.y; az[2] += (HV)*wz.z; az[3] += (HV)*wz.w; \
    an[0] += (HV)*wn.x; an[1] += (HV)*wn.y; an[2] += (HV)*wn.z; an[3] += (HV)*wn.w; \
  }
  GRU_K(h0.x, 0) GRU_K(h0.y, 1) GRU_K(h0.z, 2) GRU_K(h0.w, 3)
  GRU_K(h1.x, 4) GRU_K(h1.y, 5) GRU_K(h1.z, 6) GRU_K(h1.w, 7)
  GRU_K(h2.x, 8) GRU_K(h2.y, 9) GRU_K(h2.z, 10) GRU_K(h2.w, 11)
  GRU_K(h3.x, 12) GRU_K(h3.y, 13) GRU_K(h3.z, 14) GRU_K(h3.w, 15)
#undef GRU_K
#pragma unroll
  for (int j = 0; j < 4; ++j) {
    part[t][j] = ar[j];
    part[t][4 + j] = az[j];
    part[t][8 + j] = an[j];
  }
  __syncthreads();
  if (t < 64) {
    int c4f = e_cl >> 2, jf = e_cl & 3;
    float sr = 0.f, sz = 0.f, sn = 0.f;
#pragma unroll
    for (int p = 0; p < 32; ++p) {
      const float* pp = part[p * 16 + e_bl * 4 + c4f];
      sr += pp[jf];
      sz += pp[4 + jf];
      sn += pp[8 + jf];
    }
    int bb = bg * 4 + e_bl;
    int hh = cg * 16 + e_cl;
    float rr = 1.f / (1.f + __expf(-(ir + sr + bhr)));
    float zz = 1.f / (1.f + __expf(-(iz + sz + bhz)));
    float nn = tanhf(in_ + rr * (sn + bhn));
    hse[((long)bb * cNP1 + step + 1) * cH + hh] = (1.f - zz) * nn + zz * hold;
  }
}

// ---------------- hs -> bf16: hsb[bn][k]  AND catb upper half ----------------
__global__ void k_hscast(const float* __restrict__ hse, ushort* __restrict__ hsb,
                         ushort* __restrict__ catb) {
  int bn = blockIdx.x, t = threadIdx.x;  // 128 threads x float4
  int b = bn >> 6, n = bn & 63;
  float4 v = ((const float4*)(hse + ((long)b * cNP1 + 1 + n) * cH))[t];
  ushort4 o;
  o.x = f2bf(v.x); o.y = f2bf(v.y); o.z = f2bf(v.z); o.w = f2bf(v.w);
  *(ushort4*)(hsb + (long)bn * cH + t * 4) = o;
  *(ushort4*)(catb + (long)bn * 1024 + 512 + t * 4) = o;
}

// ---------------- q = hs @ W_att_in via MFMA ----------------
// grid (32 row-tiles, 8 col-tiles); block 256 (4 waves); tile 64x64, K=512 (8 chunks)
__global__ void __launch_bounds__(256) k_q_mfma(
    const ushort* __restrict__ hsb, const ushort* __restrict__ Bt,
    float* __restrict__ q) {
  __shared__ char lds[16384];
  int bn0 = blockIdx.x * 64, col0 = blockIdx.y * 64;
  int t = threadIdx.x;
  int w = t >> 6, lane = t & 63;
  f32x4 acc[4];
#pragma unroll
  for (int i = 0; i < 4; ++i) acc[i] = (f32x4){0.f, 0.f, 0.f, 0.f};
  int r = lane & 15, kg = lane >> 4;
  for (int kc = 0; kc < 8; ++kc) {
    int k0 = kc * 64;
#pragma unroll
    for (int p = 0; p < 2; ++p) {
      int i = t + p * 256;
      int row = i >> 3, ks = i & 7;
      float4 va = *(const float4*)(hsb + (long)(bn0 + row) * cH + k0 + ks * 8);
      *(float4*)(lds + ((row * 128 + ks * 16) ^ ((row & 7) << 4))) = va;
      float4 vb = *(const float4*)(Bt + (long)(col0 + row) * cH + k0 + ks * 8);
      *(float4*)(lds + 8192 + ((row * 128 + ks * 16) ^ ((row & 7) << 4))) = vb;
    }
    __syncthreads();
#pragma unroll
    for (int s = 0; s < 2; ++s) {
      int arow = w * 16 + r;
      bf16x8 a = *(const bf16x8*)(lds + ((arow * 128 + s * 64 + kg * 16) ^ ((arow & 7) << 4)));
#pragma unroll
      for (int cf = 0; cf < 4; ++cf) {
        int bcol = cf * 16 + r;
        bf16x8 bb = *(const bf16x8*)(lds + 8192 +
                                     ((bcol * 128 + s * 64 + kg * 16) ^ ((bcol & 7) << 4)));
        acc[cf] = __builtin_amdgcn_mfma_f32_16x16x32_bf16(a, bb, acc[cf], 0, 0, 0);
      }
    }
    __syncthreads();
  }
  int rq = lane >> 4;
#pragma unroll
  for (int cf = 0; cf < 4; ++cf) {
    int col = col0 + cf * 16 + r;
#pragma unroll
    for (int reg = 0; reg < 4; ++reg) {
      int row = bn0 + w * 16 + rq * 4 + reg;
      q[(long)row * cH + col] = acc[cf][reg];
    }
  }
}

// ---------------- causal attention v2: 4 queries/block, key early-exit ----------------
// grid (32 b, 16 qg); block 256. Writes catb lower half (bf16 context).
__global__ void k_attn2(const float* __restrict__ q, const float* __restrict__ hse,
                        ushort* __restrict__ catb) {
  __shared__ float qs[4][cH];       // 8 KB
  __shared__ float part[256][5];    // stride 5: conflict-free (gcd(5,32)=1)
  __shared__ float aw[4][cN];
  int b = blockIdx.x, qg = blockIdx.y;
  int n0 = qg * 4;
  int kmax = n0 + 3;
  int t = threadIdx.x;
  for (int i = t; i < 4 * 128; i += 256) {
    int g = i >> 7, j = i & 127;
    ((float4*)qs[g])[j] = ((const float4*)(q + (long)(b * 64 + n0 + g) * cH))[j];
  }
  __syncthreads();
  int k = t & 63, p = t >> 6;
  float s0 = 0.f, s1 = 0.f, s2 = 0.f, s3 = 0.f;
  if (k <= kmax) {
    const float* hrow = hse + ((long)b * cNP1 + 1 + k) * cH + p * 128;
    const float* q0 = &qs[0][p * 128];
    const float* q1 = &qs[1][p * 128];
    const float* q2 = &qs[2][p * 128];
    const float* q3 = &qs[3][p * 128];
#pragma unroll 4
    for (int j = 0; j < 128; ++j) {
      float hv = hrow[j];
      s0 += q0[j] * hv;
      s1 += q1[j] * hv;
      s2 += q2[j] * hv;
      s3 += q3[j] * hv;
    }
  }
  part[t][0] = s0; part[t][1] = s1; part[t][2] = s2; part[t][3] = s3;
  __syncthreads();
  if (t < 64) {
#pragma unroll
    for (int g = 0; g < 4; ++g) {
      float sc = part[t][g] + part[t + 64][g] + part[t + 128][g] + part[t + 192][g];
      if (t > n0 + g) sc = -1e30f;  // causal (ref's log(1e-45) -> exp underflow)
      float m = sc;
#pragma unroll
      for (int off = 32; off; off >>= 1) m = fmaxf(m, __shfl_xor(m, off));
      float e = __expf(sc - m);
      float sum = e;
#pragma unroll
      for (int off = 32; off; off >>= 1) sum += __shfl_xor(sum, off);
      aw[g][t] = e / sum;
    }
  }
  __syncthreads();
  float c0[4] = {0, 0, 0, 0}, c1[4] = {0, 0, 0, 0};
  for (int kk = 0; kk <= kmax; ++kk) {
    const float* hr = hse + ((long)b * cNP1 + 1 + kk) * cH;
    float h0 = hr[t], h1 = hr[t + 256];
#pragma unroll
    for (int g = 0; g < 4; ++g) {
      float a = aw[g][kk];
      c0[g] += a * h0;
      c1[g] += a * h1;
    }
  }
#pragma unroll
  for (int g = 0; g < 4; ++g) {
    long row = (long)(b * 64 + n0 + g) * 1024;
    catb[row + t] = f2bf(c0[g]);
    catb[row + t + 256] = f2bf(c1[g]);
  }
}

// ---------------- Bt[col][k] = bf16(W_att_out[k][col]) ----------------
__global__ void k_bt(const float* __restrict__ W, ushort* __restrict__ Bt) {
  int t = threadIdx.x;
  int col = blockIdx.x * 2 + (t >> 7);
  int kg = t & 127;
  ushort u[8];
#pragma unroll
  for (int j = 0; j < 8; ++j) u[j] = f2bf(W[(long)(kg * 8 + j) * cH + col]);
  int4 o;
  o.x = (int)u[0] | ((int)u[1] << 16);
  o.y = (int)u[2] | ((int)u[3] << 16);
  o.z = (int)u[4] | ((int)u[5] << 16);
  o.w = (int)u[6] | ((int)u[7] << 16);
  *(int4*)(Bt + (long)col * 1024 + kg * 8) = o;
}

// ---------------- out = tanh(cat @ W_att_out + b) via MFMA bf16 ----------------
// grid (32 row-tiles, 8 col-tiles); block 256 (4 waves); tile 64x64, K=1024 (16 chunks)
__global__ void __launch_bounds__(256) k_out_mfma(
    const ushort* __restrict__ cat, const ushort* __restrict__ Bt,
    const float* __restrict__ bias, float* __restrict__ out) {
  __shared__ char lds[16384];
  int bn0 = blockIdx.x * 64, col0 = blockIdx.y * 64;
  int t = threadIdx.x;
  int w = t >> 6, lane = t & 63;
  f32x4 acc[4];
#pragma unroll
  for (int i = 0; i < 4; ++i) acc[i] = (f32x4){0.f, 0.f, 0.f, 0.f};
  int r = lane & 15, kg = lane >> 4;
  for (int kc = 0; kc < 16; ++kc) {
    int k0 = kc * 64;
#pragma unroll
    for (int p = 0; p < 2; ++p) {
      int i = t + p * 256;
      int row = i >> 3, ks = i & 7;
      float4 va = *(const float4*)(cat + (long)(bn0 + row) * 1024 + k0 + ks * 8);
      *(float4*)(lds + ((row * 128 + ks * 16) ^ ((row & 7) << 4))) = va;
      float4 vb = *(const float4*)(Bt + (long)(col0 + row) * 1024 + k0 + ks * 8);
      *(float4*)(lds + 8192 + ((row * 128 + ks * 16) ^ ((row & 7) << 4))) = vb;
    }
    __syncthreads();
#pragma unroll
    for (int s = 0; s < 2; ++s) {
      int arow = w * 16 + r;
      bf16x8 a = *(const bf16x8*)(lds + ((arow * 128 + s * 64 + kg * 16) ^ ((arow & 7) << 4)));
#pragma unroll
      for (int cf = 0; cf < 4; ++cf) {
        int bcol = cf * 16 + r;
        bf16x8 bb = *(const bf16x8*)(lds + 8192 +
                                     ((bcol * 128 + s * 64 + kg * 16) ^ ((bcol & 7) << 4)));
        acc[cf] = __builtin_amdgcn_mfma_f32_16x16x32_bf16(a, bb, acc[cf], 0, 0, 0);
      }
    }
    __syncthreads();
  }
  int rq = lane >> 4;
#pragma unroll
  for (int cf = 0; cf < 4; ++cf) {
    int col = col0 + cf * 16 + r;
    float bv = bias[col];
#pragma unroll
    for (int reg = 0; reg < 4; ++reg) {
      int row = bn0 + w * 16 + rq * 4 + reg;
      out[(long)row * cH + col] = tanhf(acc[cf][reg] + bv);
    }
  }
}

extern "C" void kernel_launch(void* const* d_in, const int* in_sizes, int n_in,
                              void* d_out, int out_size, void* d_ws, size_t ws_size,
                              hipStream_t stream) {
  const int* sents = (const int*)d_in[0];
  const int* titles = (const int*)d_in[1];
  const float* emb = (const float*)d_in[2];
  const float* Wt = (const float*)d_in[3];
  const float* bt = (const float*)d_in[4];
  const float* W_ih = (const float*)d_in[5];
  const float* W_hh = (const float*)d_in[6];
  const float* b_ih = (const float*)d_in[7];
  const float* b_hh = (const float*)d_in[8];
  const float* W_att_in = (const float*)d_in[9];
  const float* W_att_out = (const float*)d_in[10];
  const float* b_att_out = (const float*)d_in[11];
  float* out = (float*)d_out;

  float* ws = (float*)d_ws;
  float* x = ws;                                   // (f32 region kept for layout; unused)
  float* tsum = x + (long)cBN * cD;                // B*D
  float* gi = tsum + (long)cB * cD;                // BN*3H f32 (live through scan)
  float* hse = gi + (long)cBN * cH3;               // B*65*H f32
  float* c = hse + (long)cB * cNP1 * cH;           // (f32 region kept; unused)
  ushort* xb = (ushort*)(c + (long)cBN * cH);      // 1 MB
  ushort* bti = xb + (long)cBN * cD;               // 0.75 MB
  ushort* bq = bti + (long)cH3 * cD;               // 0.5 MB
  // dead-gi aliases (after scan): q | catb | Btb | hsb  (11.4 < 12.6 MB)
  float* q = gi;
  ushort* catb = (ushort*)(gi + (long)cBN * cH);
  ushort* Btb = catb + (long)cBN * 1024;
  ushort* hsb = Btb + (long)cH * 1024;

  k_embed_x<<<cBN, 256, 0, stream>>>(sents, emb, xb);
  k_title<<<cB, 256, 0, stream>>>(titles, emb, tsum);
  k_h0<<<(cB * cH) / 256, 256, 0, stream>>>(tsum, Wt, bt, hse);
  k_bti<<<dim3(24, 4), 256, 0, stream>>>(W_ih, bti);
  k_bq<<<dim3(8, 8), 256, 0, stream>>>(W_att_in, bq);
  k_gi_mfma<<<dim3(32, 24), 256, 0, stream>>>(xb, bti, b_ih, gi);
  for (int step = 0; step < cN; ++step)
    k_gru_step<<<256, 512, 0, stream>>>(gi, W_hh, b_hh, hse, step);
  k_hscast<<<cBN, 128, 0, stream>>>(hse, hsb, catb);
  k_q_mfma<<<dim3(32, 8), 256, 0, stream>>>(hsb, bq, q);
  k_attn2<<<dim3(cB, 16), 256, 0, stream>>>(q, hse, catb);
  k_bt<<<256, 256, 0, stream>>>(W_att_out, Btb);
  k_out_mfma<<<dim3(32, 8), 256, 0, stream>>>(catb, Btb, b_att_out, out);
}